// Round 7
// baseline (441.636 us; speedup 1.0000x reference)
//
#include <hip/hip_runtime.h>
#include <math.h>

#define B 4
#define C 64
#define L 4096
#define OUTC 64
#define SCALE 10.0f
#define THRESH 1e-3f

typedef float v4f __attribute__((ext_vector_type(4)));
typedef short bf16x8 __attribute__((ext_vector_type(8)));
typedef unsigned short us8 __attribute__((ext_vector_type(8)));

__device__ __forceinline__ unsigned short f2bf(float x) {
    unsigned int u = __float_as_uint(x);
    u += 0x7fffu + ((u >> 16) & 1u);          // round-to-nearest-even
    return (unsigned short)(u >> 16);
}
__device__ __forceinline__ float bf2f(unsigned short h) {
    return __uint_as_float(((unsigned int)h) << 16);
}
__device__ __forceinline__ v4f mfma16(bf16x8 a, bf16x8 b, v4f c) {
    return __builtin_amdgcn_mfma_f32_16x16x32_bf16(a, b, c, 0, 0, 0);
}

// ---------------------------------------------------------------------------
// Projection: p = l2norm(W2 @ leaky(W1 @ x)) per column, emitted as bf16
// hi/lo planes in ROW-MAJOR [b*L + l][c] layout (c contiguous) so the scores
// kernel can load MFMA A/B fragments directly (8 contiguous c per lane).
// 512 blocks (2 inputs x 4 batches x 64 column-tiles) x 256 threads.
// ---------------------------------------------------------------------------
__global__ void __launch_bounds__(256) proj_kernel(
    const float* __restrict__ q_in, const float* __restrict__ k_in,
    const float* __restrict__ W1, const float* __restrict__ W2,
    unsigned short* __restrict__ Qh, unsigned short* __restrict__ Ql,
    unsigned short* __restrict__ Kh, unsigned short* __restrict__ Kl)
{
    int bid   = blockIdx.x;        // 0..511
    int which = bid >> 8;          // 0 = query, 1 = key
    int b     = (bid >> 6) & 3;
    int l0    = (bid & 63) << 6;
    int t     = threadIdx.x;
    int g     = t >> 6;            // 0..3
    int l     = t & 63;

    const float* __restrict__ src =
        (which ? k_in : q_in) + (size_t)b * C * L + l0 + l;
    unsigned short* __restrict__ dh = which ? Kh : Qh;
    unsigned short* __restrict__ dl = which ? Kl : Ql;

    __shared__ float Ht[128][65];   // [h][l], pad 65 -> conflict-free
    __shared__ float red[4][64];

    float xr[C];
    #pragma unroll
    for (int c = 0; c < C; ++c)
        xr[c] = src[(size_t)c * L];

    // Stage 1: H[o][l] for o in [g*32, g*32+32)
    #pragma unroll 1
    for (int oo = 0; oo < 32; oo += 4) {
        #pragma unroll
        for (int u = 0; u < 4; ++u) {
            int o = g * 32 + oo + u;
            float h0 = 0.f, h1 = 0.f, h2 = 0.f, h3 = 0.f;
            #pragma unroll
            for (int c = 0; c < C; c += 4) {
                h0 = fmaf(W1[o * C + c + 0], xr[c + 0], h0);
                h1 = fmaf(W1[o * C + c + 1], xr[c + 1], h1);
                h2 = fmaf(W1[o * C + c + 2], xr[c + 2], h2);
                h3 = fmaf(W1[o * C + c + 3], xr[c + 3], h3);
            }
            float h = (h0 + h1) + (h2 + h3);
            Ht[o][l] = (h >= 0.0f) ? h : 0.01f * h;   // LeakyReLU(0.01)
        }
    }
    __syncthreads();

    // Stage 2: Y[o][l] for o in [g*16, g*16+16)
    float y[16];
    #pragma unroll
    for (int u = 0; u < 16; ++u) y[u] = 0.f;

    #pragma unroll 1
    for (int hh = 0; hh < 2 * C; hh += 16) {
        float hr[16];
        #pragma unroll
        for (int r = 0; r < 16; ++r)
            hr[r] = Ht[hh + r][l];
        #pragma unroll
        for (int u = 0; u < 16; ++u) {
            int o = g * 16 + u;
            #pragma unroll
            for (int h = 0; h < 16; ++h)
                y[u] = fmaf(W2[o * (2 * C) + hh + h], hr[h], y[u]);
        }
    }

    // l2norm over all 64 output channels (cross-group via LDS)
    float ss = 0.f;
    #pragma unroll
    for (int u = 0; u < 16; ++u) ss = fmaf(y[u], y[u], ss);
    red[g][l] = ss;
    __syncthreads();
    float tot = red[0][l] + red[1][l] + red[2][l] + red[3][l];
    float inv = 1.0f / fmaxf(sqrtf(tot), 1e-12f);

    // Emit bf16 hi/lo split: val = hi + lo with |val-(hi+lo)| ~ 2^-18*|val|
    unsigned short hs[16], ls[16];
    #pragma unroll
    for (int u = 0; u < 16; ++u) {
        float val = y[u] * inv;
        hs[u] = f2bf(val);
        ls[u] = f2bf(val - bf2f(hs[u]));
    }
    size_t rowoff = ((size_t)b * L + l0 + l) * 64 + (size_t)g * 16;
    *(us8*)(dh + rowoff)     = *(us8*)&hs[0];
    *(us8*)(dh + rowoff + 8) = *(us8*)&hs[8];
    *(us8*)(dl + rowoff)     = *(us8*)&ls[0];
    *(us8*)(dl + rowoff + 8) = *(us8*)&ls[8];
}

// ---------------------------------------------------------------------------
// Scores via MFMA bf16x3 + softmax(fixed shift 10) + threshold.
// 512 blocks x 512 threads (8 waves); 32 q-rows per block.
// XCD-AWARE SWIZZLE: consecutive blockIdx round-robin across the 8 XCDs, so
// xcd = bid & 7 selects batch b = xcd >> 1. Each XCD then re-reads only ONE
// batch's K (Kh+Kl = 2 MB <= 4 MB per-XCD L2) instead of all four (8 MB,
// which thrashed L2 and streamed 2 GB from LLC at ~13 TB/s -> the ~150 us
// plateau of rounds 5/6). 64 blocks/XCD on 32 CUs = 2 blocks/CU.
// __launch_bounds__(512,4): <=128 VGPR -> 4 waves/SIMD. K fragments
// prefetched one ct ahead; nontemporal output stores keep K L2-resident.
// S = Qh*Kh + Qh*Kl + Ql*Kh (lo*lo dropped, ~4e-5 logit error). |S|<=10 so
// the softmax shift is the constant 10 (exp(S-10) in [2e-9,1], no max pass).
// ---------------------------------------------------------------------------
__global__ void __launch_bounds__(512, 4) scores_kernel(
    const unsigned short* __restrict__ Qh, const unsigned short* __restrict__ Ql,
    const unsigned short* __restrict__ Kh, const unsigned short* __restrict__ Kl,
    float* __restrict__ out)
{
    int bid  = blockIdx.x;          // 0..511
    int xcd  = bid & 7;             // XCD id under round-robin dispatch
    int b    = xcd >> 1;            // 2 XCDs per batch
    int rti  = ((xcd & 1) << 6) | (bid >> 3);   // 0..127 row-tile
    int r0   = rti << 5;            // 32 rows
    int t    = threadIdx.x;
    int wave = t >> 6;
    int lane = t & 63;
    int quad = lane >> 4;
    int ln   = lane & 15;

    // A fragments: aQ[rt][c0][hi/lo], m = ln, k = quad*8 + j  (m120-verified)
    bf16x8 aQ[2][2][2];
    {
        size_t qbase = ((size_t)b * L + r0) * 64;
        #pragma unroll
        for (int rt = 0; rt < 2; ++rt) {
            size_t rowb = qbase + (size_t)(rt * 16 + ln) * 64 + quad * 8;
            #pragma unroll
            for (int c0 = 0; c0 < 2; ++c0) {
                aQ[rt][c0][0] = *(const bf16x8*)(Qh + rowb + c0 * 32);
                aQ[rt][c0][1] = *(const bf16x8*)(Ql + rowb + c0 * 32);
            }
        }
    }

    const size_t kbase = (size_t)b * L * 64;
    __shared__ float wsum[32][8];
    __shared__ float rinv[32];

    // ---------------- pass 1: row sums of exp(S - 10) ----------------
    v4f ps[2];
    ps[0] = (v4f){0.f, 0.f, 0.f, 0.f};
    ps[1] = (v4f){0.f, 0.f, 0.f, 0.f};

    {
        size_t kr0 = kbase + (size_t)(wave * 512 + ln) * 64 + quad * 8;
        bf16x8 bh0 = *(const bf16x8*)(Kh + kr0);
        bf16x8 bl0 = *(const bf16x8*)(Kl + kr0);
        bf16x8 bh1 = *(const bf16x8*)(Kh + kr0 + 32);
        bf16x8 bl1 = *(const bf16x8*)(Kl + kr0 + 32);

        #pragma unroll 1
        for (int ct = 0; ct < 32; ++ct) {
            int ctn = (ct + 1) & 31;   // prefetch (wraps harmlessly)
            size_t krn = kbase + (size_t)(wave * 512 + ctn * 16 + ln) * 64 + quad * 8;
            bf16x8 nh0 = *(const bf16x8*)(Kh + krn);
            bf16x8 nl0 = *(const bf16x8*)(Kl + krn);
            bf16x8 nh1 = *(const bf16x8*)(Kh + krn + 32);
            bf16x8 nl1 = *(const bf16x8*)(Kl + krn + 32);

            #pragma unroll
            for (int rt = 0; rt < 2; ++rt) {
                v4f acc = (v4f){0.f, 0.f, 0.f, 0.f};
                acc = mfma16(aQ[rt][0][0], bh0, acc);
                acc = mfma16(aQ[rt][0][1], bh0, acc);
                acc = mfma16(aQ[rt][0][0], bl0, acc);
                acc = mfma16(aQ[rt][1][0], bh1, acc);
                acc = mfma16(aQ[rt][1][1], bh1, acc);
                acc = mfma16(aQ[rt][1][0], bl1, acc);
                #pragma unroll
                for (int r = 0; r < 4; ++r)
                    ps[rt][r] += __expf(fmaf(SCALE, acc[r], -SCALE));
            }
            bh0 = nh0; bl0 = nl0; bh1 = nh1; bl1 = nl1;
        }
    }

    // reduce over the 16 ln-lanes (cols) per row, then across waves via LDS
    #pragma unroll
    for (int rt = 0; rt < 2; ++rt) {
        #pragma unroll
        for (int r = 0; r < 4; ++r) {
            float s = ps[rt][r];
            s += __shfl_xor(s, 1);
            s += __shfl_xor(s, 2);
            s += __shfl_xor(s, 4);
            s += __shfl_xor(s, 8);
            if (ln == 0) wsum[rt * 16 + quad * 4 + r][wave] = s;
        }
    }
    __syncthreads();
    if (t < 32) {
        float s = 0.f;
        #pragma unroll
        for (int w = 0; w < 8; ++w) s += wsum[t][w];
        rinv[t] = 1.0f / s;
    }
    __syncthreads();

    float rv[2][4];
    #pragma unroll
    for (int rt = 0; rt < 2; ++rt)
        #pragma unroll
        for (int r = 0; r < 4; ++r)
            rv[rt][r] = rinv[rt * 16 + quad * 4 + r];

    // ---------------- pass 2: recompute, normalize, threshold, store ------
    float* __restrict__ outb = out + ((size_t)b * L + r0) * L;
    {
        size_t kr0 = kbase + (size_t)(wave * 512 + ln) * 64 + quad * 8;
        bf16x8 bh0 = *(const bf16x8*)(Kh + kr0);
        bf16x8 bl0 = *(const bf16x8*)(Kl + kr0);
        bf16x8 bh1 = *(const bf16x8*)(Kh + kr0 + 32);
        bf16x8 bl1 = *(const bf16x8*)(Kl + kr0 + 32);

        #pragma unroll 1
        for (int ct = 0; ct < 32; ++ct) {
            int m0  = wave * 512 + ct * 16;
            int ctn = (ct + 1) & 31;
            size_t krn = kbase + (size_t)(wave * 512 + ctn * 16 + ln) * 64 + quad * 8;
            bf16x8 nh0 = *(const bf16x8*)(Kh + krn);
            bf16x8 nl0 = *(const bf16x8*)(Kl + krn);
            bf16x8 nh1 = *(const bf16x8*)(Kh + krn + 32);
            bf16x8 nl1 = *(const bf16x8*)(Kl + krn + 32);

            #pragma unroll
            for (int rt = 0; rt < 2; ++rt) {
                v4f acc = (v4f){0.f, 0.f, 0.f, 0.f};
                acc = mfma16(aQ[rt][0][0], bh0, acc);
                acc = mfma16(aQ[rt][0][1], bh0, acc);
                acc = mfma16(aQ[rt][0][0], bl0, acc);
                acc = mfma16(aQ[rt][1][0], bh1, acc);
                acc = mfma16(aQ[rt][1][1], bh1, acc);
                acc = mfma16(aQ[rt][1][0], bl1, acc);
                #pragma unroll
                for (int r = 0; r < 4; ++r) {
                    float w = __expf(fmaf(SCALE, acc[r], -SCALE)) * rv[rt][r];
                    w = (w > THRESH) ? w : 0.f;
                    // C/D layout: col = ln, row = quad*4 + r (m89/m91)
                    __builtin_nontemporal_store(
                        w, outb + (size_t)(rt * 16 + quad * 4 + r) * L + m0 + ln);
                }
            }
            bh0 = nh0; bl0 = nl0; bh1 = nh1; bl1 = nl1;
        }
    }
}

// ---------------------------------------------------------------------------
extern "C" void kernel_launch(void* const* d_in, const int* in_sizes, int n_in,
                              void* d_out, int out_size, void* d_ws, size_t ws_size,
                              hipStream_t stream) {
    const float* query = (const float*)d_in[0];
    const float* key   = (const float*)d_in[1];
    const float* W1    = (const float*)d_in[2];
    const float* W2    = (const float*)d_in[3];
    float* out = (float*)d_out;

    // ws layout (ushorts): Qh | Ql | Kh | Kl, each B*L*OUTC = 1048576 elems
    unsigned short* Qh = (unsigned short*)d_ws;
    unsigned short* Ql = Qh + (size_t)B * L * OUTC;
    unsigned short* Kh = Ql + (size_t)B * L * OUTC;
    unsigned short* Kl = Kh + (size_t)B * L * OUTC;

    hipLaunchKernelGGL(proj_kernel, dim3(512), dim3(256), 0, stream,
                       query, key, W1, W2, Qh, Ql, Kh, Kl);
    hipLaunchKernelGGL(scores_kernel, dim3(512), dim3(512), 0, stream,
                       Qh, Ql, Kh, Kl, out);
}